// Round 7
// baseline (169.178 us; speedup 1.0000x reference)
//
#include <hip/hip_runtime.h>

typedef short bf16x8 __attribute__((ext_vector_type(8)));
typedef short bf16x4 __attribute__((ext_vector_type(4)));
typedef unsigned short u16x8 __attribute__((ext_vector_type(8)));
typedef float f32x4 __attribute__((ext_vector_type(4)));
typedef unsigned int u32x2 __attribute__((ext_vector_type(2)));

#define LOG2E 1.44269504088896340736f

__device__ __forceinline__ float bf2f(unsigned short u) {
  union { unsigned int i; float f; } v; v.i = ((unsigned int)u) << 16; return v.f;
}
__device__ __forceinline__ unsigned short f2bf(float f) {
  union { float fl; unsigned int i; } v; v.fl = f;
  unsigned int r = v.i + 0x7FFFu + ((v.i >> 16) & 1u);
  return (unsigned short)(r >> 16);
}
__device__ __forceinline__ unsigned int cvt_pk_bf16(float lo, float hi) {
  unsigned int d;
  asm("v_cvt_pk_bf16_f32 %0, %1, %2" : "=v"(d) : "v"(lo), "v"(hi));
  return d;
}
__device__ __forceinline__ void gload_lds16(const void* g, void* l) {
  __builtin_amdgcn_global_load_lds(
      (const __attribute__((address_space(1))) void*)g,
      (__attribute__((address_space(3))) void*)l, 16, 0, 0);
}

// ---------------- fused fp32 -> bf16 conversions (one launch) ----------------
__global__ __launch_bounds__(256) void cvt_all(const float* __restrict__ x,
                                               const float* __restrict__ wqkv,
                                               const float* __restrict__ wproj,
                                               const float* __restrict__ bias,
                                               unsigned short* __restrict__ xb,
                                               unsigned short* __restrict__ wqb,
                                               unsigned short* __restrict__ wpb,
                                               unsigned short* __restrict__ bb) {
  int i = blockIdx.x * 256 + threadIdx.x;  // 1,572,864 total
  const float* src; unsigned short* dst; int off; float scale = 1.0f;
  if (i < 524288)       { src = x;     dst = xb;  off = i; }
  else if (i < 917504)  { src = wqkv;  dst = wqb; off = i - 524288; }
  else if (i < 1048576) { src = wproj; dst = wpb; off = i - 917504; }
  else                  { src = bias;  dst = bb;  off = i - 1048576; scale = LOG2E; }
  float4 a = ((const float4*)src)[2 * off];
  float4 b = ((const float4*)src)[2 * off + 1];
  u16x8 o;
  o[0] = f2bf(a.x * scale); o[1] = f2bf(a.y * scale);
  o[2] = f2bf(a.z * scale); o[3] = f2bf(a.w * scale);
  o[4] = f2bf(b.x * scale); o[5] = f2bf(b.y * scale);
  o[6] = f2bf(b.z * scale); o[7] = f2bf(b.w * scale);
  ((u16x8*)dst)[off] = o;
}

// ---------------- GEMM NT: out[m][n] = sum_k A[m][k]*B[n][k] ----------------
template <bool F32OUT>
__global__ __launch_bounds__(256) void gemm_nt(const unsigned short* __restrict__ A,
                                               const unsigned short* __restrict__ B,
                                               void* __restrict__ Cout,
                                               const float* __restrict__ bias,
                                               int M, int N, int K) {
  __shared__ __align__(16) unsigned short a_lds[128 * 64];
  __shared__ __align__(16) unsigned short b_lds[128 * 64];
  const int t = threadIdx.x;
  const int lane = t & 63, w = t >> 6;
  const int wm = w >> 1, wn = w & 1;
  const int r16 = lane >> 4, c16 = lane & 15;
  const int m0 = blockIdx.y * 128, n0 = blockIdx.x * 128;
  f32x4 acc[4][4] = {};
  for (int k0 = 0; k0 < K; k0 += 64) {
#pragma unroll
    for (int i = 0; i < 4; ++i) {
      int s = i * 256 + t;
      int row = s >> 3, c = s & 7;
      int cs = c ^ (row & 7);
      gload_lds16(A + (size_t)(m0 + row) * K + k0 + cs * 8, (char*)a_lds + s * 16);
      gload_lds16(B + (size_t)(n0 + row) * K + k0 + cs * 8, (char*)b_lds + s * 16);
    }
    __syncthreads();
#pragma unroll
    for (int ks = 0; ks < 2; ++ks) {
      bf16x8 af[4], bfr[4];
#pragma unroll
      for (int mi = 0; mi < 4; ++mi) {
        int row = wm * 64 + mi * 16 + c16;
        int ch = (r16 + ks * 4) ^ (row & 7);
        af[mi] = *(const bf16x8*)&a_lds[row * 64 + ch * 8];
      }
#pragma unroll
      for (int ni = 0; ni < 4; ++ni) {
        int row = wn * 64 + ni * 16 + c16;
        int ch = (r16 + ks * 4) ^ (row & 7);
        bfr[ni] = *(const bf16x8*)&b_lds[row * 64 + ch * 8];
      }
#pragma unroll
      for (int mi = 0; mi < 4; ++mi)
#pragma unroll
        for (int ni = 0; ni < 4; ++ni)
          acc[mi][ni] = __builtin_amdgcn_mfma_f32_16x16x32_bf16(af[mi], bfr[ni], acc[mi][ni], 0, 0, 0);
    }
    __syncthreads();
  }
#pragma unroll
  for (int mi = 0; mi < 4; ++mi)
#pragma unroll
    for (int ni = 0; ni < 4; ++ni)
#pragma unroll
      for (int r = 0; r < 4; ++r) {
        int m = m0 + wm * 64 + mi * 16 + r16 * 4 + r;
        int n = n0 + wn * 64 + ni * 16 + c16;
        float v = acc[mi][ni][r];
        if constexpr (F32OUT) {
          ((float*)Cout)[(size_t)m * N + n] = v + bias[n];
        } else {
          ((unsigned short*)Cout)[(size_t)m * N + n] = f2bf(v);
        }
      }
}

// ---------------- normalize + bias + pack q,k,(v transposed) ----------------
__global__ __launch_bounds__(256) void norm_pack(const unsigned short* __restrict__ pre,
                                                 const float* __restrict__ q_bias,
                                                 const float* __restrict__ v_bias,
                                                 const float* __restrict__ scale_mul,
                                                 unsigned short* __restrict__ qo,
                                                 unsigned short* __restrict__ ko,
                                                 unsigned short* __restrict__ vto) {
  __shared__ float tl[64][65];
  const int t = threadIdx.x;
  const int li = t >> 2, dq = t & 3;
  const int tile = blockIdx.x;  // b*32 + lt
  const int sl = blockIdx.y;    // qkv*16 + h
  const int qkv = sl >> 4, h = sl & 15;
  const int b = tile >> 5, lt = tile & 31;
  const int l = lt * 64 + li;
  const int dbase = dq * 16;
  const unsigned short* src = pre + ((size_t)b * 2048 + l) * 3072 + qkv * 1024 + h * 64 + dbase;
  float v[16];
  bf16x8 x0 = *(const bf16x8*)src;
  bf16x8 x1 = *(const bf16x8*)(src + 8);
#pragma unroll
  for (int j = 0; j < 8; ++j) {
    v[j] = bf2f((unsigned short)x0[j]);
    v[8 + j] = bf2f((unsigned short)x1[j]);
  }
  if (qkv == 0) {
#pragma unroll
    for (int j = 0; j < 16; ++j) v[j] += q_bias[h * 64 + dbase + j];
  } else if (qkv == 2) {
#pragma unroll
    for (int j = 0; j < 16; ++j) v[j] += v_bias[h * 64 + dbase + j];
  }
  if (qkv < 2) {
    float ss = 0.f;
#pragma unroll
    for (int j = 0; j < 16; ++j) ss += v[j] * v[j];
    ss += __shfl_xor(ss, 1);
    ss += __shfl_xor(ss, 2);
    float inv = 1.0f / fmaxf(sqrtf(ss), 1e-12f);
    if (qkv == 0) inv *= __expf(fminf(scale_mul[h], 4.6051701859880914f));
    u16x8 o0, o1;
#pragma unroll
    for (int j = 0; j < 8; ++j) {
      o0[j] = f2bf(v[j] * inv);
      o1[j] = f2bf(v[8 + j] * inv);
    }
    unsigned short* dst = (qkv == 0 ? qo : ko) + ((size_t)(b * 16 + h) * 2048 + l) * 64 + dbase;
    *(u16x8*)dst = o0;
    *(u16x8*)(dst + 8) = o1;
  } else {
#pragma unroll
    for (int j = 0; j < 16; ++j) tl[li][dbase + j] = v[j];
    __syncthreads();
    const int d = li;
    const int lb = dq * 16;
    u16x8 o0, o1;
#pragma unroll
    for (int j = 0; j < 8; ++j) {
      o0[j] = f2bf(tl[lb + j][d]);
      o1[j] = f2bf(tl[lb + 8 + j][d]);
    }
    unsigned short* dst = vto + ((size_t)(b * 16 + h) * 64 + d) * 2048 + lt * 64 + lb;
    *(u16x8*)dst = o0;
    *(u16x8*)(dst + 8) = o1;
  }
}

// ---------------- flash attention, K-split x2, 128 q-rows/block ----------------
// R6 inner loop unchanged. KSPLIT=2: fixed-shift softmax has no running max,
// so (O, lsum) partials over K are additive -> each block does 16 iters and
// writes f32 partials; combine() sums and normalizes. bias-LDS and P-LDS are
// aliased (wave-private rows, reads strictly precede writes) -> 32 KB LDS.
__global__ __launch_bounds__(256) void attn_fwd(const unsigned short* __restrict__ qb,
                                                const unsigned short* __restrict__ kbuf,
                                                const unsigned short* __restrict__ vtb,
                                                const unsigned short* __restrict__ biasl2,
                                                float* __restrict__ op0,
                                                float* __restrict__ op1,
                                                float* __restrict__ lsum_part) {
  __shared__ __align__(16) unsigned short k_lds[64 * 64];
  __shared__ __align__(16) unsigned short vt_lds[64 * 64];
  __shared__ __align__(16) unsigned short bp_lds[128 * 64];  // bias, then P (aliased)
  const int t = threadIdx.x;
  const int lane = t & 63, w = t >> 6;
  const int r16 = lane >> 4, c16 = lane & 15;
  // XCD-aware swizzle (bijective: 1024 = 8*128)
  const int bid = blockIdx.x;
  const int swz = (bid & 7) * 128 + (bid >> 3);
  const int bh = swz >> 5;
  const int split = (swz >> 4) & 1;
  const int q0 = (swz & 15) * 128;
  const int h = bh & 15;
  const size_t qk_base = (size_t)bh * 2048 * 64;
  const int kbeg = split * 1024;
  // staging addresses
  const int srow = t >> 3;                // 0..31
  const int scs = (t & 7) ^ (srow & 7);   // pre-swizzled chunk
  const unsigned short* kp = kbuf + qk_base + (size_t)srow * 64 + scs * 8;
  const unsigned short* vp = vtb + qk_base + (size_t)srow * 2048 + scs * 8;
  const unsigned short* bp = biasl2 + (size_t)(q0 + srow) * 2048 + scs * 8;
  // Q fragments: two 16-row subtiles per wave
  bf16x8 aq[2][2];
#pragma unroll
  for (int qt = 0; qt < 2; ++qt) {
    int row = q0 + w * 32 + qt * 16 + c16;
    const unsigned short* qp = qb + qk_base + (size_t)row * 64 + r16 * 8;
    aq[qt][0] = *(const bf16x8*)qp;
    aq[qt][1] = *(const bf16x8*)(qp + 32);
  }
  f32x4 o[2][4] = {};
  float lsum[2] = {0.f, 0.f};
  const int m7 = c16 & 7;
  const int prow0 = w * 32 + c16;
  const int prow1 = w * 32 + 16 + c16;

  for (int kb0 = kbeg; kb0 < kbeg + 1024; kb0 += 64) {
    // stage K (2), V^T (2), bias (4) via global_load_lds
    gload_lds16(kp + (size_t)kb0 * 64, (char*)k_lds + t * 16);
    gload_lds16(kp + (size_t)kb0 * 64 + 32 * 64, (char*)k_lds + t * 16 + 4096);
    gload_lds16(vp + kb0, (char*)vt_lds + t * 16);
    gload_lds16(vp + kb0 + 32 * 2048, (char*)vt_lds + t * 16 + 4096);
#pragma unroll
    for (int i = 0; i < 4; ++i)
      gload_lds16(bp + kb0 + (size_t)i * 32 * 2048, (char*)bp_lds + t * 16 + i * 4096);
    __syncthreads();
    // S^T = K Q^T
    f32x4 s4[2][4] = {};
    __builtin_amdgcn_s_setprio(1);
#pragma unroll
    for (int ks = 0; ks < 2; ++ks) {
      bf16x8 bk[4];
#pragma unroll
      for (int mi = 0; mi < 4; ++mi) {
        int row = mi * 16 + c16;
        int ch = (r16 + ks * 4) ^ (row & 7);
        bk[mi] = *(const bf16x8*)&k_lds[row * 64 + ch * 8];
      }
#pragma unroll
      for (int qt = 0; qt < 2; ++qt)
#pragma unroll
        for (int mi = 0; mi < 4; ++mi)
          s4[qt][mi] = __builtin_amdgcn_mfma_f32_16x16x32_bf16(bk[mi], aq[qt][ks], s4[qt][mi], 0, 0, 0);
    }
    __builtin_amdgcn_s_setprio(0);
    // softmax numerator: p = 2^(S*log2e + bias'); bias read from bp_lds
    float p[2][4][4];
#pragma unroll
    for (int qt = 0; qt < 2; ++qt) {
      const int prow = qt ? prow1 : prow0;
#pragma unroll
      for (int mi = 0; mi < 4; ++mi) {
        int ch = (2 * mi + (r16 >> 1)) ^ m7;
        bf16x4 b4 = *(const bf16x4*)&bp_lds[prow * 64 + ch * 8 + 4 * (r16 & 1)];
#pragma unroll
        for (int r = 0; r < 4; ++r)
          p[qt][mi][r] = __builtin_amdgcn_exp2f(
              __builtin_fmaf(s4[qt][mi][r], LOG2E, bf2f((unsigned short)b4[r])));
      }
#pragma unroll
      for (int mi = 0; mi < 4; ++mi)
        lsum[qt] += (p[qt][mi][0] + p[qt][mi][1]) + (p[qt][mi][2] + p[qt][mi][3]);
    }
    // pack P -> same bp_lds addresses just consumed (wave-private rows)
#pragma unroll
    for (int qt = 0; qt < 2; ++qt) {
      const int prow = qt ? prow1 : prow0;
#pragma unroll
      for (int mi = 0; mi < 4; ++mi) {
        u32x2 pk2;
        pk2[0] = cvt_pk_bf16(p[qt][mi][0], p[qt][mi][1]);
        pk2[1] = cvt_pk_bf16(p[qt][mi][2], p[qt][mi][3]);
        int ch = (2 * mi + (r16 >> 1)) ^ m7;
        ((u32x2*)bp_lds)[prow * 16 + ch * 2 + (r16 & 1)] = pk2;
      }
    }
    // O += P V
    __builtin_amdgcn_s_setprio(1);
#pragma unroll
    for (int ks = 0; ks < 2; ++ks) {
      bf16x8 ap[2];
#pragma unroll
      for (int qt = 0; qt < 2; ++qt) {
        const int prow = qt ? prow1 : prow0;
        int ch = (4 * ks + r16) ^ m7;
        ap[qt] = *(const bf16x8*)&bp_lds[prow * 64 + ch * 8];
      }
#pragma unroll
      for (int nd = 0; nd < 4; ++nd) {
        int drow = nd * 16 + c16;
        int chv = (r16 + ks * 4) ^ (drow & 7);
        bf16x8 bv = *(const bf16x8*)&vt_lds[drow * 64 + chv * 8];
#pragma unroll
        for (int qt = 0; qt < 2; ++qt)
          o[qt][nd] = __builtin_amdgcn_mfma_f32_16x16x32_bf16(ap[qt], bv, o[qt][nd], 0, 0, 0);
      }
    }
    __builtin_amdgcn_s_setprio(0);
    __syncthreads();
  }
  // epilogue: store f32 partials + lsum partial (no normalization here)
  float* op = split ? op1 : op0;
#pragma unroll
  for (int qt = 0; qt < 2; ++qt) {
    float ls = lsum[qt];
    ls += __shfl_xor(ls, 16);
    ls += __shfl_xor(ls, 32);
    if (r16 == 0)
      lsum_part[(size_t)split * 65536 + (size_t)bh * 2048 + q0 + w * 32 + qt * 16 + c16] = ls;
    const int qrow_g = q0 + w * 32 + qt * 16 + r16 * 4;
#pragma unroll
    for (int r = 0; r < 4; ++r)
#pragma unroll
      for (int nd = 0; nd < 4; ++nd)
        op[((size_t)bh * 2048 + qrow_g + r) * 64 + nd * 16 + c16] = o[qt][nd][r];
  }
}

// ---------------- combine K-split partials, normalize, write bf16 ----------------
__global__ __launch_bounds__(256) void combine(const float* __restrict__ op0,
                                               const float* __restrict__ op1,
                                               const float* __restrict__ lsum_part,
                                               unsigned short* __restrict__ oup) {
  int gid = blockIdx.x * 256 + threadIdx.x;  // 524,288
  int d0 = (gid & 7) * 8;
  int bhl = gid >> 3;
  int l = bhl & 2047, bh = bhl >> 11;
  int b = bh >> 4, h = bh & 15;
  size_t obase = ((size_t)bh * 2048 + l) * 64 + d0;
  float4 a0 = ((const float4*)(op0 + obase))[0];
  float4 a1 = ((const float4*)(op0 + obase))[1];
  float4 c0 = ((const float4*)(op1 + obase))[0];
  float4 c1 = ((const float4*)(op1 + obase))[1];
  float inv = 1.0f / (lsum_part[(size_t)bh * 2048 + l] + lsum_part[65536 + (size_t)bh * 2048 + l]);
  u16x8 o;
  o[0] = f2bf((a0.x + c0.x) * inv); o[1] = f2bf((a0.y + c0.y) * inv);
  o[2] = f2bf((a0.z + c0.z) * inv); o[3] = f2bf((a0.w + c0.w) * inv);
  o[4] = f2bf((a1.x + c1.x) * inv); o[5] = f2bf((a1.y + c1.y) * inv);
  o[6] = f2bf((a1.z + c1.z) * inv); o[7] = f2bf((a1.w + c1.w) * inv);
  *(u16x8*)(oup + ((size_t)b * 2048 + l) * 1024 + h * 64 + d0) = o;
}

extern "C" void kernel_launch(void* const* d_in, const int* in_sizes, int n_in,
                              void* d_out, int out_size, void* d_ws, size_t ws_size,
                              hipStream_t stream) {
  const float* x = (const float*)d_in[0];
  const float* attn_bias = (const float*)d_in[1];
  const float* W_qkv = (const float*)d_in[2];
  const float* q_bias = (const float*)d_in[3];
  const float* v_bias = (const float*)d_in[4];
  const float* scale_mul = (const float*)d_in[5];
  const float* W_proj = (const float*)d_in[6];
  const float* b_proj = (const float*)d_in[7];
  float* out = (float*)d_out;
  char* ws = (char*)d_ws;

  // workspace layout (with dead-region reuse for K-split partials)
  unsigned short* x_bf = (unsigned short*)(ws + 0);            // 8 MB (dead after gemm1)
  unsigned short* wqkv_bf = (unsigned short*)(ws + 8388608);   // 6 MB (dead after gemm1)
  unsigned short* bias_bf = (unsigned short*)(ws + 16777216);  // 8 MB
  unsigned short* q_pk = (unsigned short*)(ws + 25165824);     // 8 MB
  unsigned short* k_pk = (unsigned short*)(ws + 33554432);     // 8 MB
  unsigned short* vt_pk = (unsigned short*)(ws + 41943040);    // 8 MB
  unsigned short* oup_bf = (unsigned short*)(ws + 50331648);   // 8 MB
  unsigned short* pre_qkv = (unsigned short*)(ws + 58720256);  // 24 MB (dead after norm_pack)
  float* o_part0 = (float*)(ws + 58720256);                    // 16 MB over pre_qkv
  float* o_part1 = (float*)(ws + 0);                           // 16 MB over x_bf+wqkv_bf (+2MB pad)
  unsigned short* wproj_bf = (unsigned short*)(ws + 83886080); // 2 MB @ 80 MB
  float* lsum_part = (float*)(ws + 85983232);                  // 512 KB @ 82 MB

  cvt_all<<<6144, 256, 0, stream>>>(x, W_qkv, W_proj, attn_bias,
                                    x_bf, wqkv_bf, wproj_bf, bias_bf);
  gemm_nt<false><<<dim3(24, 32), 256, 0, stream>>>(x_bf, wqkv_bf, (void*)pre_qkv, nullptr,
                                                   4096, 3072, 1024);
  norm_pack<<<dim3(64, 48), 256, 0, stream>>>(pre_qkv, q_bias, v_bias, scale_mul,
                                              q_pk, k_pk, vt_pk);
  attn_fwd<<<1024, 256, 0, stream>>>(q_pk, k_pk, vt_pk, bias_bf,
                                     o_part0, o_part1, lsum_part);
  combine<<<2048, 256, 0, stream>>>(o_part0, o_part1, lsum_part, oup_bf);
  gemm_nt<true><<<dim3(8, 32), 256, 0, stream>>>(oup_bf, wproj_bf, (void*)out, b_proj,
                                                 4096, 1024, 1024);
}

// Round 8
// 156.467 us; speedup vs baseline: 1.0812x; 1.0812x over previous
//
#include <hip/hip_runtime.h>

typedef short bf16x8 __attribute__((ext_vector_type(8)));
typedef unsigned short u16x8 __attribute__((ext_vector_type(8)));
typedef float f32x4 __attribute__((ext_vector_type(4)));
typedef float f32x16 __attribute__((ext_vector_type(16)));
typedef unsigned int u32x2 __attribute__((ext_vector_type(2)));

#define LOG2E 1.44269504088896340736f

__device__ __forceinline__ float bf2f(unsigned short u) {
  union { unsigned int i; float f; } v; v.i = ((unsigned int)u) << 16; return v.f;
}
__device__ __forceinline__ unsigned short f2bf(float f) {
  union { float fl; unsigned int i; } v; v.fl = f;
  unsigned int r = v.i + 0x7FFFu + ((v.i >> 16) & 1u);
  return (unsigned short)(r >> 16);
}
__device__ __forceinline__ unsigned int cvt_pk_bf16(float lo, float hi) {
  unsigned int d;
  asm("v_cvt_pk_bf16_f32 %0, %1, %2" : "=v"(d) : "v"(lo), "v"(hi));
  return d;
}
// swap D.lanes[32:63] <-> S.lanes[0:31] (HK T12 order: swap(pk(r0,r1), pk(r4,r5)))
__device__ __forceinline__ void perm_swap(unsigned int& a, unsigned int& b) {
  asm("v_permlane32_swap_b32 %0, %1" : "+v"(a), "+v"(b));
}
__device__ __forceinline__ bf16x8 mk8(unsigned int a, unsigned int b,
                                      unsigned int c, unsigned int d) {
  union { unsigned int u[4]; bf16x8 v; } r;
  r.u[0] = a; r.u[1] = b; r.u[2] = c; r.u[3] = d;
  return r.v;
}
__device__ __forceinline__ void gload_lds16(const void* g, void* l) {
  __builtin_amdgcn_global_load_lds(
      (const __attribute__((address_space(1))) void*)g,
      (__attribute__((address_space(3))) void*)l, 16, 0, 0);
}

// ---------------- fused fp32 -> bf16 conversions (x, W_qkv, W_proj) ----------------
__global__ __launch_bounds__(256) void cvt_all(const float* __restrict__ x,
                                               const float* __restrict__ wqkv,
                                               const float* __restrict__ wproj,
                                               unsigned short* __restrict__ xb,
                                               unsigned short* __restrict__ wqb,
                                               unsigned short* __restrict__ wpb) {
  int i = blockIdx.x * 256 + threadIdx.x;  // 1,048,576 total (x8 units)
  const float* src; unsigned short* dst; int off;
  if (i < 524288)       { src = x;     dst = xb;  off = i; }
  else if (i < 917504)  { src = wqkv;  dst = wqb; off = i - 524288; }
  else                  { src = wproj; dst = wpb; off = i - 917504; }
  float4 a = ((const float4*)src)[2 * off];
  float4 b = ((const float4*)src)[2 * off + 1];
  u16x8 o;
  o[0] = f2bf(a.x); o[1] = f2bf(a.y); o[2] = f2bf(a.z); o[3] = f2bf(a.w);
  o[4] = f2bf(b.x); o[5] = f2bf(b.y); o[6] = f2bf(b.z); o[7] = f2bf(b.w);
  ((u16x8*)dst)[off] = o;
}

// ---------------- bias -> per-lane MFMA-accumulator-ordered layout ----------------
// biasArr flat elem = (((qt*32+kb)*4+w)*64+l)*32 + kg*16 + r  where the attn lane l
// of wave w (q-tile qt) at iter kb reads its 32 values (kg,r) as 4 contiguous b128.
// Value = bias[q][k]*log2e with q = qt*128+w*32+(l&31),
// k = kb*64 + kg*32 + (r&3) + 8*(r>>2) + 4*(l>>5).
__global__ __launch_bounds__(256) void prep_bias(const float* __restrict__ bias,
                                                 unsigned short* __restrict__ biasArr) {
  int tid = blockIdx.x * 256 + threadIdx.x;  // 262,144
  int kg = tid & 1;
  int l = (tid >> 1) & 63;
  int w = (tid >> 7) & 3;
  int kb = (tid >> 9) & 31;
  int qt = (tid >> 14) & 15;
  int q = qt * 128 + w * 32 + (l & 31);
  int kbase = kb * 64 + kg * 32 + (l >> 5) * 4;
  const float* src = bias + (size_t)q * 2048 + kbase;
  u16x8 oa, ob;
#pragma unroll
  for (int rr = 0; rr < 4; ++rr) {
    float4 g = *(const float4*)(src + rr * 8);
    unsigned short e0 = f2bf(g.x * LOG2E), e1 = f2bf(g.y * LOG2E);
    unsigned short e2 = f2bf(g.z * LOG2E), e3 = f2bf(g.w * LOG2E);
    if (rr < 2) {
      oa[rr * 4 + 0] = e0; oa[rr * 4 + 1] = e1; oa[rr * 4 + 2] = e2; oa[rr * 4 + 3] = e3;
    } else {
      ob[(rr - 2) * 4 + 0] = e0; ob[(rr - 2) * 4 + 1] = e1;
      ob[(rr - 2) * 4 + 2] = e2; ob[(rr - 2) * 4 + 3] = e3;
    }
  }
  ((u16x8*)biasArr)[tid * 2] = oa;
  ((u16x8*)biasArr)[tid * 2 + 1] = ob;
}

// ---------------- GEMM NT: out[m][n] = sum_k A[m][k]*B[n][k] ----------------
template <bool F32OUT>
__global__ __launch_bounds__(256) void gemm_nt(const unsigned short* __restrict__ A,
                                               const unsigned short* __restrict__ B,
                                               void* __restrict__ Cout,
                                               const float* __restrict__ bias,
                                               int M, int N, int K) {
  __shared__ __align__(16) unsigned short a_lds[128 * 64];
  __shared__ __align__(16) unsigned short b_lds[128 * 64];
  const int t = threadIdx.x;
  const int lane = t & 63, w = t >> 6;
  const int wm = w >> 1, wn = w & 1;
  const int r16 = lane >> 4, c16 = lane & 15;
  const int m0 = blockIdx.y * 128, n0 = blockIdx.x * 128;
  f32x4 acc[4][4] = {};
  for (int k0 = 0; k0 < K; k0 += 64) {
#pragma unroll
    for (int i = 0; i < 4; ++i) {
      int s = i * 256 + t;
      int row = s >> 3, c = s & 7;
      int cs = c ^ (row & 7);
      gload_lds16(A + (size_t)(m0 + row) * K + k0 + cs * 8, (char*)a_lds + s * 16);
      gload_lds16(B + (size_t)(n0 + row) * K + k0 + cs * 8, (char*)b_lds + s * 16);
    }
    __syncthreads();
#pragma unroll
    for (int ks = 0; ks < 2; ++ks) {
      bf16x8 af[4], bfr[4];
#pragma unroll
      for (int mi = 0; mi < 4; ++mi) {
        int row = wm * 64 + mi * 16 + c16;
        int ch = (r16 + ks * 4) ^ (row & 7);
        af[mi] = *(const bf16x8*)&a_lds[row * 64 + ch * 8];
      }
#pragma unroll
      for (int ni = 0; ni < 4; ++ni) {
        int row = wn * 64 + ni * 16 + c16;
        int ch = (r16 + ks * 4) ^ (row & 7);
        bfr[ni] = *(const bf16x8*)&b_lds[row * 64 + ch * 8];
      }
#pragma unroll
      for (int mi = 0; mi < 4; ++mi)
#pragma unroll
        for (int ni = 0; ni < 4; ++ni)
          acc[mi][ni] = __builtin_amdgcn_mfma_f32_16x16x32_bf16(af[mi], bfr[ni], acc[mi][ni], 0, 0, 0);
    }
    __syncthreads();
  }
#pragma unroll
  for (int mi = 0; mi < 4; ++mi)
#pragma unroll
    for (int ni = 0; ni < 4; ++ni)
#pragma unroll
      for (int r = 0; r < 4; ++r) {
        int m = m0 + wm * 64 + mi * 16 + r16 * 4 + r;
        int n = n0 + wn * 64 + ni * 16 + c16;
        float v = acc[mi][ni][r];
        if constexpr (F32OUT) {
          ((float*)Cout)[(size_t)m * N + n] = v + bias[n];
        } else {
          ((unsigned short*)Cout)[(size_t)m * N + n] = f2bf(v);
        }
      }
}

// ---------------- normalize + bias + pack q,k,(v transposed) ----------------
__global__ __launch_bounds__(256) void norm_pack(const unsigned short* __restrict__ pre,
                                                 const float* __restrict__ q_bias,
                                                 const float* __restrict__ v_bias,
                                                 const float* __restrict__ scale_mul,
                                                 unsigned short* __restrict__ qo,
                                                 unsigned short* __restrict__ ko,
                                                 unsigned short* __restrict__ vto) {
  __shared__ float tl[64][65];
  const int t = threadIdx.x;
  const int li = t >> 2, dq = t & 3;
  const int tile = blockIdx.x;  // b*32 + lt
  const int sl = blockIdx.y;    // qkv*16 + h
  const int qkv = sl >> 4, h = sl & 15;
  const int b = tile >> 5, lt = tile & 31;
  const int l = lt * 64 + li;
  const int dbase = dq * 16;
  const unsigned short* src = pre + ((size_t)b * 2048 + l) * 3072 + qkv * 1024 + h * 64 + dbase;
  float v[16];
  bf16x8 x0 = *(const bf16x8*)src;
  bf16x8 x1 = *(const bf16x8*)(src + 8);
#pragma unroll
  for (int j = 0; j < 8; ++j) {
    v[j] = bf2f((unsigned short)x0[j]);
    v[8 + j] = bf2f((unsigned short)x1[j]);
  }
  if (qkv == 0) {
#pragma unroll
    for (int j = 0; j < 16; ++j) v[j] += q_bias[h * 64 + dbase + j];
  } else if (qkv == 2) {
#pragma unroll
    for (int j = 0; j < 16; ++j) v[j] += v_bias[h * 64 + dbase + j];
  }
  if (qkv < 2) {
    float ss = 0.f;
#pragma unroll
    for (int j = 0; j < 16; ++j) ss += v[j] * v[j];
    ss += __shfl_xor(ss, 1);
    ss += __shfl_xor(ss, 2);
    float inv = 1.0f / fmaxf(sqrtf(ss), 1e-12f);
    if (qkv == 0) inv *= __expf(fminf(scale_mul[h], 4.6051701859880914f));
    u16x8 o0, o1;
#pragma unroll
    for (int j = 0; j < 8; ++j) {
      o0[j] = f2bf(v[j] * inv);
      o1[j] = f2bf(v[8 + j] * inv);
    }
    unsigned short* dst = (qkv == 0 ? qo : ko) + ((size_t)(b * 16 + h) * 2048 + l) * 64 + dbase;
    *(u16x8*)dst = o0;
    *(u16x8*)(dst + 8) = o1;
  } else {
#pragma unroll
    for (int j = 0; j < 16; ++j) tl[li][dbase + j] = v[j];
    __syncthreads();
    const int d = li;
    const int lb = dq * 16;
    u16x8 o0, o1;
#pragma unroll
    for (int j = 0; j < 8; ++j) {
      o0[j] = f2bf(tl[lb + j][d]);
      o1[j] = f2bf(tl[lb + 8 + j][d]);
    }
    unsigned short* dst = vto + ((size_t)(b * 16 + h) * 64 + d) * 2048 + lt * 64 + lb;
    *(u16x8*)dst = o0;
    *(u16x8*)(dst + 8) = o1;
  }
}

// ---------------- flash attention: 32x32 MFMA, in-register P ----------------
// 4 waves x 32 q-rows = 128 q/block, KVBLK=64 (32 iters). LDS holds K,V^T
// pre-arranged in frag-linear order (ds_read_b128 = base + frag*1024 + lane*16,
// conflict-free). S^T in 32x32 C-layout (col=q=lane&31, row=k). Softmax is
// lane-local; P becomes the PV B-fragment via cvt_pk_bf16 + permlane32_swap
// (no LDS round trip). Bias pre-arranged per-lane (prep_bias), read from global.
__global__ __launch_bounds__(256) void attn_fwd(const unsigned short* __restrict__ qb,
                                                const unsigned short* __restrict__ kbuf,
                                                const unsigned short* __restrict__ vtb,
                                                const unsigned short* __restrict__ biasArr,
                                                unsigned short* __restrict__ oup) {
  __shared__ __align__(16) unsigned short k_lds[4096];   // 8 KB: 8 frags x 1 KB
  __shared__ __align__(16) unsigned short vt_lds[4096];  // 8 KB
  const int t = threadIdx.x;
  const int lane = t & 63, w = t >> 6;
  const int l31 = lane & 31, hi = lane >> 5;
  // XCD swizzle (bijective: 512 = 8*64), bh-major within each XCD chunk
  const int bid = blockIdx.x;
  const int swz = (bid & 7) * 64 + (bid >> 3);
  const int bh = swz >> 4;
  const int qt = swz & 15;
  const int q0 = qt * 128;
  const int h = bh & 15;
  const size_t base = (size_t)bh * 2048 * 64;
  // staging sources (pre-permuted so LDS dest t*16 holds frag-linear data):
  // K frag (kg,dc): lane l -> K[kg*32+(l&31)][dc*16+(l>>5)*8]; thread t stages
  // frag dc=(t>>6) lane l=(t&63) (first gload: kg=0; second: kg=1).
  const unsigned short* kp = kbuf + base + (size_t)(t & 31) * 64 +
                             ((t >> 6) & 3) * 16 + ((t >> 5) & 1) * 8;
  // V^T frag (dg,kc): lane l -> V^T[dg*32+(l&31)][kc*16+(l>>5)*8]
  const unsigned short* vp = vtb + base + (size_t)(t & 31) * 2048 +
                             ((t >> 6) & 3) * 16 + ((t >> 5) & 1) * 8;
  const unsigned short* bp = biasArr + (size_t)qt * 262144 + w * 2048 + lane * 32;
  // Q fragments (B-operand): lane l -> Q[q0+w*32+(l&31)][dc*16+(l>>5)*8]
  bf16x8 qf[4];
  {
    const unsigned short* qp = qb + base + (size_t)(q0 + w * 32 + l31) * 64 + hi * 8;
    qf[0] = *(const bf16x8*)qp;
    qf[1] = *(const bf16x8*)(qp + 16);
    qf[2] = *(const bf16x8*)(qp + 32);
    qf[3] = *(const bf16x8*)(qp + 48);
  }
  f32x16 o0 = {}, o1 = {};
  float ls0 = 0.f, ls1 = 0.f;

  for (int kb = 0; kb < 32; ++kb) {
    // stage K (2), V^T (2) into frag-linear LDS
    gload_lds16(kp + (size_t)kb * 4096, (char*)k_lds + t * 16);
    gload_lds16(kp + (size_t)kb * 4096 + 2048, (char*)k_lds + t * 16 + 4096);
    gload_lds16(vp + kb * 64, (char*)vt_lds + t * 16);
    gload_lds16(vp + kb * 64 + 32 * 2048, (char*)vt_lds + t * 16 + 4096);
    __syncthreads();
    // bias: 64 B/lane, coalesced global (latency hidden under QK^T)
    const unsigned short* bq = bp + (size_t)kb * 8192;
    bf16x8 b0 = *(const bf16x8*)bq;
    bf16x8 b1 = *(const bf16x8*)(bq + 8);
    bf16x8 b2 = *(const bf16x8*)(bq + 16);
    bf16x8 b3 = *(const bf16x8*)(bq + 24);
    // S^T = K Q^T : s0 = k-rows 0..31, s1 = 32..63 (col q = lane&31)
    f32x16 s0 = {}, s1 = {};
    __builtin_amdgcn_s_setprio(1);
#pragma unroll
    for (int dc = 0; dc < 4; ++dc) {
      bf16x8 kf0 = *(const bf16x8*)&k_lds[dc * 512 + lane * 8];
      bf16x8 kf1 = *(const bf16x8*)&k_lds[(4 + dc) * 512 + lane * 8];
      s0 = __builtin_amdgcn_mfma_f32_32x32x16_bf16(kf0, qf[dc], s0, 0, 0, 0);
      s1 = __builtin_amdgcn_mfma_f32_32x32x16_bf16(kf1, qf[dc], s1, 0, 0, 0);
    }
    __builtin_amdgcn_s_setprio(0);
    // p = exp2(S*log2e + bias'); lane-local (row k = (r&3)+8*(r>>2)+4*hi)
    float p0[16], p1[16];
#pragma unroll
    for (int r = 0; r < 8; ++r) {
      p0[r] = __builtin_amdgcn_exp2f(__builtin_fmaf(s0[r], LOG2E, bf2f((unsigned short)b0[r])));
      p0[8 + r] = __builtin_amdgcn_exp2f(__builtin_fmaf(s0[8 + r], LOG2E, bf2f((unsigned short)b1[r])));
      p1[r] = __builtin_amdgcn_exp2f(__builtin_fmaf(s1[r], LOG2E, bf2f((unsigned short)b2[r])));
      p1[8 + r] = __builtin_amdgcn_exp2f(__builtin_fmaf(s1[8 + r], LOG2E, bf2f((unsigned short)b3[r])));
    }
#pragma unroll
    for (int r = 0; r < 16; ++r) { ls0 += p0[r]; ls1 += p1[r]; }
    // P -> PV B-frags in-register: pack pairs, swap halves (T12)
    unsigned int x0 = cvt_pk_bf16(p0[0], p0[1]), x1 = cvt_pk_bf16(p0[2], p0[3]);
    unsigned int y0 = cvt_pk_bf16(p0[4], p0[5]), y1 = cvt_pk_bf16(p0[6], p0[7]);
    unsigned int z0 = cvt_pk_bf16(p0[8], p0[9]), z1 = cvt_pk_bf16(p0[10], p0[11]);
    unsigned int w0 = cvt_pk_bf16(p0[12], p0[13]), w1 = cvt_pk_bf16(p0[14], p0[15]);
    perm_swap(x0, y0); perm_swap(x1, y1); perm_swap(z0, w0); perm_swap(z1, w1);
    bf16x8 pf0 = mk8(x0, x1, y0, y1);  // k' 0..15 of this iter
    bf16x8 pf1 = mk8(z0, z1, w0, w1);  // k' 16..31
    unsigned int a0 = cvt_pk_bf16(p1[0], p1[1]), a1 = cvt_pk_bf16(p1[2], p1[3]);
    unsigned int c0 = cvt_pk_bf16(p1[4], p1[5]), c1 = cvt_pk_bf16(p1[6], p1[7]);
    unsigned int d0 = cvt_pk_bf16(p1[8], p1[9]), d1 = cvt_pk_bf16(p1[10], p1[11]);
    unsigned int e0 = cvt_pk_bf16(p1[12], p1[13]), e1 = cvt_pk_bf16(p1[14], p1[15]);
    perm_swap(a0, c0); perm_swap(a1, c1); perm_swap(d0, e0); perm_swap(d1, e1);
    bf16x8 pf2 = mk8(a0, a1, c0, c1);  // k' 32..47
    bf16x8 pf3 = mk8(d0, d1, e0, e1);  // k' 48..63
    // O^T += V^T P^T (d-rows: o0 = 0..31, o1 = 32..63)
    bf16x8 pf[4] = {pf0, pf1, pf2, pf3};
    __builtin_amdgcn_s_setprio(1);
#pragma unroll
    for (int kc = 0; kc < 4; ++kc) {
      bf16x8 vf0 = *(const bf16x8*)&vt_lds[kc * 512 + lane * 8];
      bf16x8 vf1 = *(const bf16x8*)&vt_lds[(4 + kc) * 512 + lane * 8];
      o0 = __builtin_amdgcn_mfma_f32_32x32x16_bf16(vf0, pf[kc], o0, 0, 0, 0);
      o1 = __builtin_amdgcn_mfma_f32_32x32x16_bf16(vf1, pf[kc], o1, 0, 0, 0);
    }
    __builtin_amdgcn_s_setprio(0);
    __syncthreads();
  }
  // epilogue: lsum over hi halves, normalize, write
  float lsum = ls0 + ls1;
  lsum += __shfl_xor(lsum, 32);
  float inv = 1.0f / lsum;
  const int b = bh >> 4;
  unsigned short* orow = oup + ((size_t)b * 2048 + q0 + w * 32 + l31) * 1024 + h * 64;
#pragma unroll
  for (int dg = 0; dg < 2; ++dg) {
#pragma unroll
    for (int rr = 0; rr < 4; ++rr) {
      float v0 = (dg ? o1[rr * 4 + 0] : o0[rr * 4 + 0]) * inv;
      float v1 = (dg ? o1[rr * 4 + 1] : o0[rr * 4 + 1]) * inv;
      float v2 = (dg ? o1[rr * 4 + 2] : o0[rr * 4 + 2]) * inv;
      float v3 = (dg ? o1[rr * 4 + 3] : o0[rr * 4 + 3]) * inv;
      u32x2 pk2;
      pk2[0] = cvt_pk_bf16(v0, v1);
      pk2[1] = cvt_pk_bf16(v2, v3);
      int d = dg * 32 + rr * 8 + hi * 4;
      *(u32x2*)(orow + d) = pk2;
    }
  }
}

extern "C" void kernel_launch(void* const* d_in, const int* in_sizes, int n_in,
                              void* d_out, int out_size, void* d_ws, size_t ws_size,
                              hipStream_t stream) {
  const float* x = (const float*)d_in[0];
  const float* attn_bias = (const float*)d_in[1];
  const float* W_qkv = (const float*)d_in[2];
  const float* q_bias = (const float*)d_in[3];
  const float* v_bias = (const float*)d_in[4];
  const float* scale_mul = (const float*)d_in[5];
  const float* W_proj = (const float*)d_in[6];
  const float* b_proj = (const float*)d_in[7];
  float* out = (float*)d_out;
  char* ws = (char*)d_ws;

  unsigned short* x_bf = (unsigned short*)(ws + 0);            //  8 MB
  unsigned short* wqkv_bf = (unsigned short*)(ws + 8388608);   //  6 MB
  unsigned short* wproj_bf = (unsigned short*)(ws + 14680064); //  2 MB
  unsigned short* biasArr = (unsigned short*)(ws + 16777216);  //  8 MB (arranged, *log2e)
  unsigned short* q_pk = (unsigned short*)(ws + 25165824);     //  8 MB
  unsigned short* k_pk = (unsigned short*)(ws + 33554432);     //  8 MB
  unsigned short* vt_pk = (unsigned short*)(ws + 41943040);    //  8 MB
  unsigned short* oup_bf = (unsigned short*)(ws + 50331648);   //  8 MB
  unsigned short* pre_qkv = (unsigned short*)(ws + 58720256);  // 24 MB

  cvt_all<<<4096, 256, 0, stream>>>(x, W_qkv, W_proj, x_bf, wqkv_bf, wproj_bf);
  prep_bias<<<1024, 256, 0, stream>>>(attn_bias, biasArr);
  gemm_nt<false><<<dim3(24, 32), 256, 0, stream>>>(x_bf, wqkv_bf, (void*)pre_qkv, nullptr,
                                                   4096, 3072, 1024);
  norm_pack<<<dim3(64, 48), 256, 0, stream>>>(pre_qkv, q_bias, v_bias, scale_mul,
                                              q_pk, k_pk, vt_pk);
  attn_fwd<<<512, 256, 0, stream>>>(q_pk, k_pk, vt_pk, biasArr, oup_bf);
  gemm_nt<true><<<dim3(8, 32), 256, 0, stream>>>(oup_bf, wproj_bf, (void*)out, b_proj,
                                                 4096, 1024, 1024);
}

// Round 9
// 151.678 us; speedup vs baseline: 1.1154x; 1.0316x over previous
//
#include <hip/hip_runtime.h>

typedef short bf16x8 __attribute__((ext_vector_type(8)));
typedef unsigned short u16x8 __attribute__((ext_vector_type(8)));
typedef float f32x4 __attribute__((ext_vector_type(4)));
typedef float f32x16 __attribute__((ext_vector_type(16)));
typedef unsigned int u32x2 __attribute__((ext_vector_type(2)));

#define LOG2E 1.44269504088896340736f

__device__ __forceinline__ float bf2f(unsigned short u) {
  union { unsigned int i; float f; } v; v.i = ((unsigned int)u) << 16; return v.f;
}
__device__ __forceinline__ unsigned short f2bf(float f) {
  union { float fl; unsigned int i; } v; v.fl = f;
  unsigned int r = v.i + 0x7FFFu + ((v.i >> 16) & 1u);
  return (unsigned short)(r >> 16);
}
__device__ __forceinline__ unsigned int cvt_pk_bf16(float lo, float hi) {
  unsigned int d;
  asm("v_cvt_pk_bf16_f32 %0, %1, %2" : "=v"(d) : "v"(lo), "v"(hi));
  return d;
}
__device__ __forceinline__ void perm_swap(unsigned int& a, unsigned int& b) {
  asm("v_permlane32_swap_b32 %0, %1" : "+v"(a), "+v"(b));
}
__device__ __forceinline__ bf16x8 mk8(unsigned int a, unsigned int b,
                                      unsigned int c, unsigned int d) {
  union { unsigned int u[4]; bf16x8 v; } r;
  r.u[0] = a; r.u[1] = b; r.u[2] = c; r.u[3] = d;
  return r.v;
}
__device__ __forceinline__ void gload_lds16(const void* g, void* l) {
  __builtin_amdgcn_global_load_lds(
      (const __attribute__((address_space(1))) void*)g,
      (__attribute__((address_space(3))) void*)l, 16, 0, 0);
}

// ---------------- fused fp32 -> bf16 conversions (x, W_qkv, W_proj) ----------------
__global__ __launch_bounds__(256) void cvt_all(const float* __restrict__ x,
                                               const float* __restrict__ wqkv,
                                               const float* __restrict__ wproj,
                                               unsigned short* __restrict__ xb,
                                               unsigned short* __restrict__ wqb,
                                               unsigned short* __restrict__ wpb) {
  int i = blockIdx.x * 256 + threadIdx.x;  // 1,048,576 total (x8 units)
  const float* src; unsigned short* dst; int off;
  if (i < 524288)       { src = x;     dst = xb;  off = i; }
  else if (i < 917504)  { src = wqkv;  dst = wqb; off = i - 524288; }
  else                  { src = wproj; dst = wpb; off = i - 917504; }
  float4 a = ((const float4*)src)[2 * off];
  float4 b = ((const float4*)src)[2 * off + 1];
  u16x8 o;
  o[0] = f2bf(a.x); o[1] = f2bf(a.y); o[2] = f2bf(a.z); o[3] = f2bf(a.w);
  o[4] = f2bf(b.x); o[5] = f2bf(b.y); o[6] = f2bf(b.z); o[7] = f2bf(b.w);
  ((u16x8*)dst)[off] = o;
}

// ---------------- bias -> frag-linear DMA-ordered layout ----------------
// Slice (qt,kb) is 16 KB contiguous, organized as [w][c][lane] 16B chunks:
// chunk index = ((qt*32+kb)*4 + w)*256 + c*64 + l  (c = within-lane chunk 0..3).
// Lane l of wave w reads its 32 values (m = c*8+e) as 4x ds_read_b128 at
// b_lds + w*4096B + c*1024B + l*16B. Value = bias[q][k]*log2e with
// q = qt*128 + w*32 + (l&31), k = kb*64 + kg*32 + (r&3)+8*(r>>2)+4*(l>>5),
// where m = kg*16 + r.
__global__ __launch_bounds__(256) void prep_bias(const float* __restrict__ bias,
                                                 unsigned short* __restrict__ biasArr) {
  int tid = blockIdx.x * 256 + threadIdx.x;  // 262,144 = (qt,kb,w,l,kg)
  int kg = tid & 1;
  int l = (tid >> 1) & 63;
  int w = (tid >> 7) & 3;
  int kb = (tid >> 9) & 31;
  int qt = (tid >> 14) & 15;
  int q = qt * 128 + w * 32 + (l & 31);
  int kbase = kb * 64 + kg * 32 + (l >> 5) * 4;
  const float* src = bias + (size_t)q * 2048 + kbase;
  u16x8 oa, ob;
#pragma unroll
  for (int rr = 0; rr < 4; ++rr) {
    float4 g = *(const float4*)(src + rr * 8);
    unsigned short e0 = f2bf(g.x * LOG2E), e1 = f2bf(g.y * LOG2E);
    unsigned short e2 = f2bf(g.z * LOG2E), e3 = f2bf(g.w * LOG2E);
    if (rr < 2) {
      oa[rr * 4 + 0] = e0; oa[rr * 4 + 1] = e1; oa[rr * 4 + 2] = e2; oa[rr * 4 + 3] = e3;
    } else {
      ob[(rr - 2) * 4 + 0] = e0; ob[(rr - 2) * 4 + 1] = e1;
      ob[(rr - 2) * 4 + 2] = e2; ob[(rr - 2) * 4 + 3] = e3;
    }
  }
  // chunk c = kg*2 + {0,1}; u16x8 index = (((qt*32+kb)*4+w)*4 + c)*64 + l
  int base = (((qt * 32 + kb) * 4 + w) * 4 + kg * 2) * 64 + l;
  ((u16x8*)biasArr)[base] = oa;
  ((u16x8*)biasArr)[base + 64] = ob;
}

// ---------------- GEMM NT: out[m][n] = sum_k A[m][k]*B[n][k] ----------------
template <bool F32OUT>
__global__ __launch_bounds__(256) void gemm_nt(const unsigned short* __restrict__ A,
                                               const unsigned short* __restrict__ B,
                                               void* __restrict__ Cout,
                                               const float* __restrict__ bias,
                                               int M, int N, int K) {
  __shared__ __align__(16) unsigned short a_lds[128 * 64];
  __shared__ __align__(16) unsigned short b_lds[128 * 64];
  const int t = threadIdx.x;
  const int lane = t & 63, w = t >> 6;
  const int wm = w >> 1, wn = w & 1;
  const int r16 = lane >> 4, c16 = lane & 15;
  const int m0 = blockIdx.y * 128, n0 = blockIdx.x * 128;
  f32x4 acc[4][4] = {};
  for (int k0 = 0; k0 < K; k0 += 64) {
#pragma unroll
    for (int i = 0; i < 4; ++i) {
      int s = i * 256 + t;
      int row = s >> 3, c = s & 7;
      int cs = c ^ (row & 7);
      gload_lds16(A + (size_t)(m0 + row) * K + k0 + cs * 8, (char*)a_lds + s * 16);
      gload_lds16(B + (size_t)(n0 + row) * K + k0 + cs * 8, (char*)b_lds + s * 16);
    }
    __syncthreads();
#pragma unroll
    for (int ks = 0; ks < 2; ++ks) {
      bf16x8 af[4], bfr[4];
#pragma unroll
      for (int mi = 0; mi < 4; ++mi) {
        int row = wm * 64 + mi * 16 + c16;
        int ch = (r16 + ks * 4) ^ (row & 7);
        af[mi] = *(const bf16x8*)&a_lds[row * 64 + ch * 8];
      }
#pragma unroll
      for (int ni = 0; ni < 4; ++ni) {
        int row = wn * 64 + ni * 16 + c16;
        int ch = (r16 + ks * 4) ^ (row & 7);
        bfr[ni] = *(const bf16x8*)&b_lds[row * 64 + ch * 8];
      }
#pragma unroll
      for (int mi = 0; mi < 4; ++mi)
#pragma unroll
        for (int ni = 0; ni < 4; ++ni)
          acc[mi][ni] = __builtin_amdgcn_mfma_f32_16x16x32_bf16(af[mi], bfr[ni], acc[mi][ni], 0, 0, 0);
    }
    __syncthreads();
  }
#pragma unroll
  for (int mi = 0; mi < 4; ++mi)
#pragma unroll
    for (int ni = 0; ni < 4; ++ni)
#pragma unroll
      for (int r = 0; r < 4; ++r) {
        int m = m0 + wm * 64 + mi * 16 + r16 * 4 + r;
        int n = n0 + wn * 64 + ni * 16 + c16;
        float v = acc[mi][ni][r];
        if constexpr (F32OUT) {
          ((float*)Cout)[(size_t)m * N + n] = v + bias[n];
        } else {
          ((unsigned short*)Cout)[(size_t)m * N + n] = f2bf(v);
        }
      }
}

// ---------------- normalize + bias + pack q,k,(v transposed) ----------------
__global__ __launch_bounds__(256) void norm_pack(const unsigned short* __restrict__ pre,
                                                 const float* __restrict__ q_bias,
                                                 const float* __restrict__ v_bias,
                                                 const float* __restrict__ scale_mul,
                                                 unsigned short* __restrict__ qo,
                                                 unsigned short* __restrict__ ko,
                                                 unsigned short* __restrict__ vto) {
  __shared__ float tl[64][65];
  const int t = threadIdx.x;
  const int li = t >> 2, dq = t & 3;
  const int tile = blockIdx.x;  // b*32 + lt
  const int sl = blockIdx.y;    // qkv*16 + h
  const int qkv = sl >> 4, h = sl & 15;
  const int b = tile >> 5, lt = tile & 31;
  const int l = lt * 64 + li;
  const int dbase = dq * 16;
  const unsigned short* src = pre + ((size_t)b * 2048 + l) * 3072 + qkv * 1024 + h * 64 + dbase;
  float v[16];
  bf16x8 x0 = *(const bf16x8*)src;
  bf16x8 x1 = *(const bf16x8*)(src + 8);
#pragma unroll
  for (int j = 0; j < 8; ++j) {
    v[j] = bf2f((unsigned short)x0[j]);
    v[8 + j] = bf2f((unsigned short)x1[j]);
  }
  if (qkv == 0) {
#pragma unroll
    for (int j = 0; j < 16; ++j) v[j] += q_bias[h * 64 + dbase + j];
  } else if (qkv == 2) {
#pragma unroll
    for (int j = 0; j < 16; ++j) v[j] += v_bias[h * 64 + dbase + j];
  }
  if (qkv < 2) {
    float ss = 0.f;
#pragma unroll
    for (int j = 0; j < 16; ++j) ss += v[j] * v[j];
    ss += __shfl_xor(ss, 1);
    ss += __shfl_xor(ss, 2);
    float inv = 1.0f / fmaxf(sqrtf(ss), 1e-12f);
    if (qkv == 0) inv *= __expf(fminf(scale_mul[h], 4.6051701859880914f));
    u16x8 o0, o1;
#pragma unroll
    for (int j = 0; j < 8; ++j) {
      o0[j] = f2bf(v[j] * inv);
      o1[j] = f2bf(v[8 + j] * inv);
    }
    unsigned short* dst = (qkv == 0 ? qo : ko) + ((size_t)(b * 16 + h) * 2048 + l) * 64 + dbase;
    *(u16x8*)dst = o0;
    *(u16x8*)(dst + 8) = o1;
  } else {
#pragma unroll
    for (int j = 0; j < 16; ++j) tl[li][dbase + j] = v[j];
    __syncthreads();
    const int d = li;
    const int lb = dq * 16;
    u16x8 o0, o1;
#pragma unroll
    for (int j = 0; j < 8; ++j) {
      o0[j] = f2bf(tl[lb + j][d]);
      o1[j] = f2bf(tl[lb + 8 + j][d]);
    }
    unsigned short* dst = vto + ((size_t)(b * 16 + h) * 64 + d) * 2048 + lt * 64 + lb;
    *(u16x8*)dst = o0;
    *(u16x8*)(dst + 8) = o1;
  }
}

// ---------------- flash attention: 32x32 MFMA, in-register P, bias via DMA ----------------
// 4 waves x 32 q-rows = 128 q/block, KVBLK=64 (32 iters). K, V^T, AND bias all
// staged through global_load_lds (frag-linear, conflict-free b128 reads), so no
// post-barrier global latency sits on the critical path. S^T in 32x32 C-layout
// (col=q=lane&31); softmax lane-local; P -> PV B-frag via cvt_pk + permlane32_swap.
__global__ __launch_bounds__(256) void attn_fwd(const unsigned short* __restrict__ qb,
                                                const unsigned short* __restrict__ kbuf,
                                                const unsigned short* __restrict__ vtb,
                                                const unsigned short* __restrict__ biasArr,
                                                unsigned short* __restrict__ oup) {
  __shared__ __align__(16) unsigned short k_lds[4096];   //  8 KB
  __shared__ __align__(16) unsigned short vt_lds[4096];  //  8 KB
  __shared__ __align__(16) unsigned short b_lds[8192];   // 16 KB
  const int t = threadIdx.x;
  const int lane = t & 63, w = t >> 6;
  const int l31 = lane & 31, hi = lane >> 5;
  const int bid = blockIdx.x;
  const int swz = (bid & 7) * 64 + (bid >> 3);
  const int bh = swz >> 4;
  const int qt = swz & 15;
  const int q0 = qt * 128;
  const int h = bh & 15;
  const size_t base = (size_t)bh * 2048 * 64;
  // staging sources (pre-permuted global, linear LDS dest)
  const unsigned short* kp = kbuf + base + (size_t)(t & 31) * 64 +
                             ((t >> 6) & 3) * 16 + ((t >> 5) & 1) * 8;
  const unsigned short* vp = vtb + base + (size_t)(t & 31) * 2048 +
                             ((t >> 6) & 3) * 16 + ((t >> 5) & 1) * 8;
  const unsigned short* bsrc = biasArr + (size_t)qt * 262144 + t * 8;  // + kb*8192 + i*2048
  // Q fragments (B-operand)
  bf16x8 qf[4];
  {
    const unsigned short* qp = qb + base + (size_t)(q0 + w * 32 + l31) * 64 + hi * 8;
    qf[0] = *(const bf16x8*)qp;
    qf[1] = *(const bf16x8*)(qp + 16);
    qf[2] = *(const bf16x8*)(qp + 32);
    qf[3] = *(const bf16x8*)(qp + 48);
  }
  f32x16 o0 = {}, o1 = {};
  float ls0 = 0.f, ls1 = 0.f;
  const unsigned short* bl = b_lds + w * 2048 + lane * 8;  // + c*512

  for (int kb = 0; kb < 32; ++kb) {
    // stage K (2), V^T (2), bias (4) into frag-linear LDS
    gload_lds16(kp + (size_t)kb * 4096, (char*)k_lds + t * 16);
    gload_lds16(kp + (size_t)kb * 4096 + 2048, (char*)k_lds + t * 16 + 4096);
    gload_lds16(vp + kb * 64, (char*)vt_lds + t * 16);
    gload_lds16(vp + kb * 64 + 32 * 2048, (char*)vt_lds + t * 16 + 4096);
#pragma unroll
    for (int i = 0; i < 4; ++i)
      gload_lds16(bsrc + kb * 8192 + i * 2048, (char*)b_lds + t * 16 + i * 4096);
    __syncthreads();
    // S^T = K Q^T : s0 = k-rows 0..31, s1 = 32..63 (col q = lane&31)
    f32x16 s0 = {}, s1 = {};
    __builtin_amdgcn_s_setprio(1);
#pragma unroll
    for (int dc = 0; dc < 4; ++dc) {
      bf16x8 kf0 = *(const bf16x8*)&k_lds[dc * 512 + lane * 8];
      bf16x8 kf1 = *(const bf16x8*)&k_lds[(4 + dc) * 512 + lane * 8];
      s0 = __builtin_amdgcn_mfma_f32_32x32x16_bf16(kf0, qf[dc], s0, 0, 0, 0);
      s1 = __builtin_amdgcn_mfma_f32_32x32x16_bf16(kf1, qf[dc], s1, 0, 0, 0);
    }
    __builtin_amdgcn_s_setprio(0);
    // bias from LDS (conflict-free b128s), then p = exp2(S*log2e + bias')
    bf16x8 b0 = *(const bf16x8*)(bl);
    bf16x8 b1 = *(const bf16x8*)(bl + 512);
    bf16x8 b2 = *(const bf16x8*)(bl + 1024);
    bf16x8 b3 = *(const bf16x8*)(bl + 1536);
    float p0[16], p1[16];
#pragma unroll
    for (int r = 0; r < 8; ++r) {
      p0[r] = __builtin_amdgcn_exp2f(__builtin_fmaf(s0[r], LOG2E, bf2f((unsigned short)b0[r])));
      p0[8 + r] = __builtin_amdgcn_exp2f(__builtin_fmaf(s0[8 + r], LOG2E, bf2f((unsigned short)b1[r])));
      p1[r] = __builtin_amdgcn_exp2f(__builtin_fmaf(s1[r], LOG2E, bf2f((unsigned short)b2[r])));
      p1[8 + r] = __builtin_amdgcn_exp2f(__builtin_fmaf(s1[8 + r], LOG2E, bf2f((unsigned short)b3[r])));
    }
#pragma unroll
    for (int r = 0; r < 16; ++r) { ls0 += p0[r]; ls1 += p1[r]; }
    // P -> PV B-frags in-register (cvt_pk + permlane32_swap)
    unsigned int x0 = cvt_pk_bf16(p0[0], p0[1]), x1 = cvt_pk_bf16(p0[2], p0[3]);
    unsigned int y0 = cvt_pk_bf16(p0[4], p0[5]), y1 = cvt_pk_bf16(p0[6], p0[7]);
    unsigned int z0 = cvt_pk_bf16(p0[8], p0[9]), z1 = cvt_pk_bf16(p0[10], p0[11]);
    unsigned int w0 = cvt_pk_bf16(p0[12], p0[13]), w1 = cvt_pk_bf16(p0[14], p0[15]);
    perm_swap(x0, y0); perm_swap(x1, y1); perm_swap(z0, w0); perm_swap(z1, w1);
    bf16x8 pf0 = mk8(x0, x1, y0, y1);
    bf16x8 pf1 = mk8(z0, z1, w0, w1);
    unsigned int a0 = cvt_pk_bf16(p1[0], p1[1]), a1 = cvt_pk_bf16(p1[2], p1[3]);
    unsigned int c0 = cvt_pk_bf16(p1[4], p1[5]), c1 = cvt_pk_bf16(p1[6], p1[7]);
    unsigned int d0 = cvt_pk_bf16(p1[8], p1[9]), d1 = cvt_pk_bf16(p1[10], p1[11]);
    unsigned int e0 = cvt_pk_bf16(p1[12], p1[13]), e1 = cvt_pk_bf16(p1[14], p1[15]);
    perm_swap(a0, c0); perm_swap(a1, c1); perm_swap(d0, e0); perm_swap(d1, e1);
    bf16x8 pf2 = mk8(a0, a1, c0, c1);
    bf16x8 pf3 = mk8(d0, d1, e0, e1);
    // O^T += V^T P^T
    bf16x8 pf[4] = {pf0, pf1, pf2, pf3};
    __builtin_amdgcn_s_setprio(1);
#pragma unroll
    for (int kc = 0; kc < 4; ++kc) {
      bf16x8 vf0 = *(const bf16x8*)&vt_lds[kc * 512 + lane * 8];
      bf16x8 vf1 = *(const bf16x8*)&vt_lds[(4 + kc) * 512 + lane * 8];
      o0 = __builtin_amdgcn_mfma_f32_32x32x16_bf16(vf0, pf[kc], o0, 0, 0, 0);
      o1 = __builtin_amdgcn_mfma_f32_32x32x16_bf16(vf1, pf[kc], o1, 0, 0, 0);
    }
    __builtin_amdgcn_s_setprio(0);
    __syncthreads();
  }
  // epilogue
  float lsum = ls0 + ls1;
  lsum += __shfl_xor(lsum, 32);
  float inv = 1.0f / lsum;
  const int b = bh >> 4;
  unsigned short* orow = oup + ((size_t)b * 2048 + q0 + w * 32 + l31) * 1024 + h * 64;
#pragma unroll
  for (int dg = 0; dg < 2; ++dg) {
#pragma unroll
    for (int rr = 0; rr < 4; ++rr) {
      float v0 = (dg ? o1[rr * 4 + 0] : o0[rr * 4 + 0]) * inv;
      float v1 = (dg ? o1[rr * 4 + 1] : o0[rr * 4 + 1]) * inv;
      float v2 = (dg ? o1[rr * 4 + 2] : o0[rr * 4 + 2]) * inv;
      float v3 = (dg ? o1[rr * 4 + 3] : o0[rr * 4 + 3]) * inv;
      u32x2 pk2;
      pk2[0] = cvt_pk_bf16(v0, v1);
      pk2[1] = cvt_pk_bf16(v2, v3);
      int d = dg * 32 + rr * 8 + hi * 4;
      *(u32x2*)(orow + d) = pk2;
    }
  }
}

extern "C" void kernel_launch(void* const* d_in, const int* in_sizes, int n_in,
                              void* d_out, int out_size, void* d_ws, size_t ws_size,
                              hipStream_t stream) {
  const float* x = (const float*)d_in[0];
  const float* attn_bias = (const float*)d_in[1];
  const float* W_qkv = (const float*)d_in[2];
  const float* q_bias = (const float*)d_in[3];
  const float* v_bias = (const float*)d_in[4];
  const float* scale_mul = (const float*)d_in[5];
  const float* W_proj = (const float*)d_in[6];
  const float* b_proj = (const float*)d_in[7];
  float* out = (float*)d_out;
  char* ws = (char*)d_ws;

  unsigned short* x_bf = (unsigned short*)(ws + 0);            //  8 MB
  unsigned short* wqkv_bf = (unsigned short*)(ws + 8388608);   //  6 MB
  unsigned short* wproj_bf = (unsigned short*)(ws + 14680064); //  2 MB
  unsigned short* biasArr = (unsigned short*)(ws + 16777216);  //  8 MB (DMA-ordered, *log2e)
  unsigned short* q_pk = (unsigned short*)(ws + 25165824);     //  8 MB
  unsigned short* k_pk = (unsigned short*)(ws + 33554432);     //  8 MB
  unsigned short* vt_pk = (unsigned short*)(ws + 41943040);    //  8 MB
  unsigned short* oup_bf = (unsigned short*)(ws + 50331648);   //  8 MB
  unsigned short* pre_qkv = (unsigned short*)(ws + 58720256);  // 24 MB

  cvt_all<<<4096, 256, 0, stream>>>(x, W_qkv, W_proj, x_bf, wqkv_bf, wproj_bf);
  prep_bias<<<1024, 256, 0, stream>>>(attn_bias, biasArr);
  gemm_nt<false><<<dim3(24, 32), 256, 0, stream>>>(x_bf, wqkv_bf, (void*)pre_qkv, nullptr,
                                                   4096, 3072, 1024);
  norm_pack<<<dim3(64, 48), 256, 0, stream>>>(pre_qkv, q_bias, v_bias, scale_mul,
                                              q_pk, k_pk, vt_pk);
  attn_fwd<<<512, 256, 0, stream>>>(q_pk, k_pk, vt_pk, biasArr, oup_bf);
  gemm_nt<true><<<dim3(8, 32), 256, 0, stream>>>(oup_bf, wproj_bf, (void*)out, b_proj,
                                                 4096, 1024, 1024);
}